// Round 16
// baseline (176.444 us; speedup 1.0000x reference)
//
#include <hip/hip_runtime.h>
#include <math.h>

#define NN 4096
#define DD 256
#define EPSV 1e-4f
#define STABV 1e-8f
#define AVAL (1.0f / 4096.0f)
#define BVAL (1.0f / 4096.0f)
#define MAX_IT 2000
#define NB 512           // coop grid: 512 blocks x 512 thr
#define RPB 8            // rows (and cols) owned per block
#define UFLOW_M 192.0f   // if min(C)*|nrs| >= this, every exp() underflows to exactly 0.0f

typedef __attribute__((ext_vector_type(4))) float f32x4;
typedef __attribute__((ext_vector_type(8))) short bf16x8;

__device__ inline unsigned short f2bf(float f) {   // RNE f32->bf16
    unsigned u = __float_as_uint(f);
    return (unsigned short)((u + 0x7fffu + ((u >> 16) & 1u)) >> 16);
}
__device__ inline float bflo(unsigned w) { return __uint_as_float(w << 16); }
__device__ inline float bfhi(unsigned w) { return __uint_as_float(w & 0xffff0000u); }

// ---- MALL-coherent (cache-bypassing) access for cross-block data inside coop kernel ----
__device__ __forceinline__ void st_sys_f32(float* p, float v) {
    asm volatile("global_store_dword %0, %1, off sc0 sc1" :: "v"(p), "v"(v) : "memory");
}
__device__ __forceinline__ void st_sys_f32x4(float* p, f32x4 v) {
    asm volatile("global_store_dwordx4 %0, %1, off sc0 sc1" :: "v"(p), "v"(v) : "memory");
}
__device__ __forceinline__ float ld_sys_f32(const float* p) {
    float r;
    asm volatile("global_load_dword %0, %1, off sc0 sc1\n\ts_waitcnt vmcnt(0)"
                 : "=v"(r) : "v"(p) : "memory");
    return r;
}
__device__ __forceinline__ f32x4 ld_sys_f32x4(const float* p) {
    f32x4 r;
    asm volatile("global_load_dwordx4 %0, %1, off sc0 sc1\n\ts_waitcnt vmcnt(0)"
                 : "=v"(r) : "v"(p) : "memory");
    return r;
}

// ---------------- conv f32->bf16 + row norms + zero control state ----------------
__global__ __launch_bounds__(256) void sk_conv_kernel(const float* __restrict__ x,
                                                      const float* __restrict__ y,
                                                      unsigned short* __restrict__ xb,
                                                      unsigned short* __restrict__ yb,
                                                      float* __restrict__ x2,
                                                      float* __restrict__ y2,
                                                      float* __restrict__ sumC,
                                                      unsigned* __restrict__ minb,
                                                      unsigned* __restrict__ flags,
                                                      unsigned* __restrict__ bar) {
    int w = blockIdx.x * 4 + (threadIdx.x >> 6);   // row id 0..8191
    int lane = threadIdx.x & 63;
    const float* src = (w < NN) ? (x + (size_t)w * DD) : (y + (size_t)(w - NN) * DD);
    unsigned short* dst = (w < NN) ? (xb + (size_t)w * DD) : (yb + (size_t)(w - NN) * DD);
    float4 v = *(const float4*)(src + lane * 4);
    float sq = v.x * v.x + v.y * v.y + v.z * v.z + v.w * v.w;
    ushort4 p;
    p.x = f2bf(v.x); p.y = f2bf(v.y); p.z = f2bf(v.z); p.w = f2bf(v.w);
    *(ushort4*)(dst + lane * 4) = p;
#pragma unroll
    for (int off = 32; off > 0; off >>= 1) sq += __shfl_down(sq, off, 64);
    if (lane == 0) {
        if (w < NN) x2[w] = sq; else y2[w - NN] = sq;
    }
    int t = threadIdx.x;
    if (blockIdx.x == 0) {
        if (t == 0) { sumC[0] = 0.0f; minb[0] = 0xFFFFFFFFu; flags[0] = 0u; flags[1] = 0u; }
        for (int i = t; i < 384; i += 256) bar[i] = 0u;
    }
}

// ---------------- MFMA GEMM-reduce, one-shot K=256: sum(C), min(C); C NOT materialized ----------------
// 64x64 tile per block (4096 blocks), whole K staged once (A 32 KB + B 32 KB, contiguous
// copies -> perfectly coalesced), ONE vmcnt drain + barrier, then 32 MFMAs/wave straight
// through. Inputs (4 MB bf16 total) fit in each XCD's 4 MB L2 -> re-reads are L2-served.
__global__ __launch_bounds__(256, 2) void sk_gemm_kernel(const unsigned short* __restrict__ xb,
                                                         const unsigned short* __restrict__ yb,
                                                         const float* __restrict__ x2,
                                                         const float* __restrict__ y2,
                                                         float* __restrict__ sumC,
                                                         unsigned* __restrict__ minb) {
    extern __shared__ __attribute__((aligned(128))) char L[];  // 65536: As 32768 | Bs 32768
    char* As = L;                       // 64 rows x 512 B (K=256 bf16), row-major
    char* Bs = L + 32768;               // 64 cols x 512 B
    const int tid = threadIdx.x;
    const int wid = tid >> 6, lane = tid & 63;
    const int rb0 = blockIdx.y * 64, cb0 = blockIdx.x * 64;
    const int lr = lane & 15;
    const int lq = lane >> 4;
    const int wy = wid;                 // wave owns rows [wy*16, wy*16+16)

    // ---- stage whole tiles: A rows rb0..rb0+64 (32 KB contiguous), B cols cb0.. (32 KB) ----
#pragma unroll
    for (int i = 0; i < 8; ++i) {
        const int o = wid * 8192 + i * 1024;          // wave-uniform LDS offset
        const char* ga = (const char*)xb + (size_t)rb0 * 512 + o + lane * 16;
        __builtin_amdgcn_global_load_lds(
            (const __attribute__((address_space(1))) void*)ga,
            (__attribute__((address_space(3))) void*)(As + o), 16, 0, 0);
    }
#pragma unroll
    for (int i = 0; i < 8; ++i) {
        const int o = wid * 8192 + i * 1024;
        const char* gb = (const char*)yb + (size_t)cb0 * 512 + o + lane * 16;
        __builtin_amdgcn_global_load_lds(
            (const __attribute__((address_space(1))) void*)gb,
            (__attribute__((address_space(3))) void*)(Bs + o), 16, 0, 0);
    }
    asm volatile("s_waitcnt vmcnt(0)" ::: "memory");
    __syncthreads();                    // the ONLY staging barrier

    // ---- MFMA: 8 K-substeps x 4 col-tiles, acc = x.y^T partial ----
    f32x4 acc[4];
    const f32x4 z4 = {0.0f, 0.0f, 0.0f, 0.0f};
#pragma unroll
    for (int tx = 0; tx < 4; ++tx) acc[tx] = z4;
#pragma unroll
    for (int m = 0; m < 8; ++m) {
        bf16x8 af = *(const bf16x8*)(As + (wy * 16 + lr) * 512 + m * 64 + lq * 16);
#pragma unroll
        for (int tx = 0; tx < 4; ++tx) {
            bf16x8 bf = *(const bf16x8*)(Bs + (tx * 16 + lr) * 512 + m * 64 + lq * 16);
            acc[tx] = __builtin_amdgcn_mfma_f32_16x16x32_bf16(af, bf, acc[tx], 0, 0, 0);
        }
    }

    // ---- epilogue: c = sqrt(max(x2+y2-2S,0)); wave shuffle-reduce; block reduce in reused LDS ----
    float lsum = 0.0f, lmin = 3.0e38f;
    const int qr = lq * 4;
    float x2r[4];
#pragma unroll
    for (int r = 0; r < 4; ++r) x2r[r] = x2[rb0 + wy * 16 + qr + r];
#pragma unroll
    for (int tx = 0; tx < 4; ++tx) {
        int col = cb0 + tx * 16 + lr;
        float y2c = y2[col];
#pragma unroll
        for (int r = 0; r < 4; ++r) {
            float sq = x2r[r] + y2c - 2.0f * acc[tx][r];
            float c = sqrtf(fmaxf(sq, 0.0f));
            lsum += c;
            lmin = fminf(lmin, c);
        }
    }
#pragma unroll
    for (int off = 32; off > 0; off >>= 1) {
        lsum += __shfl_down(lsum, off, 64);
        lmin = fminf(lmin, __shfl_down(lmin, off, 64));
    }
    __syncthreads();                    // all waves done reading As/Bs; reuse as scratch
    float* red = (float*)L;
    if (lane == 0) { red[wid] = lsum; red[8 + wid] = lmin; }
    __syncthreads();
    if (tid == 0) {
        float s = red[0] + red[1] + red[2] + red[3];
        float mn = fminf(fminf(red[8], red[9]), fminf(red[10], red[11]));
        atomicAdd(sumC, s);
        atomicMin(minb, __float_as_uint(mn));   // C >= 0: uint order == float order
    }
}

// ---- fence-free hierarchical grid barrier (cross-block data uses sc0sc1 / atomics) ----
__device__ __forceinline__ void gridbar(unsigned* bar, unsigned target) {
    asm volatile("s_waitcnt vmcnt(0)" ::: "memory");
    __syncthreads();
    if (threadIdx.x == 0) {
        const int sg = blockIdx.x & 7;
        const unsigned bps = NB >> 3;
        unsigned p = __hip_atomic_fetch_add(&bar[sg * 32], 1u, __ATOMIC_RELAXED, __HIP_MEMORY_SCOPE_AGENT);
        if (p == target * bps - 1u) {
            unsigned q = __hip_atomic_fetch_add(&bar[256], 1u, __ATOMIC_RELAXED, __HIP_MEMORY_SCOPE_AGENT);
            if (q == target * 8u - 1u)
                __hip_atomic_store(&bar[288], target, __ATOMIC_RELAXED, __HIP_MEMORY_SCOPE_AGENT);
        }
        while (__hip_atomic_load(&bar[288], __ATOMIC_RELAXED, __HIP_MEMORY_SCOPE_AGENT) < target)
            __builtin_amdgcn_s_sleep(1);
    }
    __syncthreads();
}

// ---------------- Sinkhorn finalize ----------------
// Fast path (min(C)*|nrs| >= UFLOW_M): every exp underflows to exactly 0.0f in f32 =>
// K == 0 bitwise => u = a/stab, v = b/stab (fixed point at it=2), cost = 0. Analytic.
// Generic fallback: recompute owned C rows from xb/yb into LDS, run verified iteration loop.
__global__ __launch_bounds__(512, 4) void sk_coop_kernel(const unsigned short* __restrict__ xb,
                                                         const unsigned short* __restrict__ yb,
                                                         const float* __restrict__ x2,
                                                         const float* __restrict__ y2,
                                                         float* __restrict__ u,
                                                         float* __restrict__ v,
                                                         float* __restrict__ ksump,
                                                         float* __restrict__ wsred,
                                                         const float* __restrict__ sumC,
                                                         const unsigned* __restrict__ minb,
                                                         unsigned* __restrict__ flags,
                                                         float* __restrict__ costpart,
                                                         unsigned* __restrict__ bar,
                                                         float* __restrict__ out) {
    extern __shared__ char Cs[];       // 65536 B: 8 rows x 8192 B (bf16 x 4096), fallback only
    const int t = threadIdx.x;         // 0..511
    const int bid = blockIdx.x;
    const int r8 = t >> 6;             // wave id 0..7 == owned row index
    const int lane = t & 63;
    const float mean = sumC[0] * (1.0f / ((float)NN * (float)NN));
    const float nrs = -1.0f / (mean * EPSV);   // K = exp(C_raw * nrs), nrs < 0
    const float invMean = 1.0f / mean;
    const int r0 = bid * RPB;
    unsigned bars = 0;

    // ---- underflow fast path (grid-uniform branch) ----
    const float minC = __uint_as_float(minb[0]);
    const float m = minC * (-nrs);
    if (m >= UFLOW_M) {
        const float uval = AVAL / (0.0f + STABV);
        const float vval = BVAL / (0.0f + STABV);
        if (lane == 0) out[1 + r0 + r8] = uval;
        if (t < RPB) out[1 + NN + r0 + t] = vval;
        if (bid == 0 && t == 0) out[0] = 0.0f;
        return;
    }

    // ================= generic fallback (not taken for this input) =================
    {
        float x2r[8];
#pragma unroll
        for (int r = 0; r < RPB; ++r) x2r[r] = x2[r0 + r];
        float cp[8] = {0, 0, 0, 0, 0, 0, 0, 0};
        for (int r = 0; r < RPB; ++r) {
            alignas(16) unsigned short crow[8];
#pragma unroll
            for (int q = 0; q < 8; ++q) {
                int j = t * 8 + q;
                float s = 0.0f;
                for (int k = 0; k < DD; k += 8) {
                    uint4 xa = *(const uint4*)(xb + (size_t)(r0 + r) * DD + k);
                    uint4 ya = *(const uint4*)(yb + (size_t)j * DD + k);
                    s += bflo(xa.x) * bflo(ya.x) + bfhi(xa.x) * bfhi(ya.x);
                    s += bflo(xa.y) * bflo(ya.y) + bfhi(xa.y) * bfhi(ya.y);
                    s += bflo(xa.z) * bflo(ya.z) + bfhi(xa.z) * bfhi(ya.z);
                    s += bflo(xa.w) * bflo(ya.w) + bfhi(xa.w) * bfhi(ya.w);
                }
                float c = sqrtf(fmaxf(x2r[r] + y2[j] - 2.0f * s, 0.0f));
                unsigned short cb = f2bf(c);
                crow[q] = cb;
                cp[q] += __expf(bflo((unsigned)cb) * nrs);
            }
            *(uint4*)(Cs + r * 8192 + t * 16) = *(const uint4*)crow;
        }
        f32x4 c0 = {cp[0], cp[1], cp[2], cp[3]};
        f32x4 c1 = {cp[4], cp[5], cp[6], cp[7]};
        st_sys_f32x4(ksump + (size_t)bid * NN + t * 8, c0);
        st_sys_f32x4(ksump + (size_t)bid * NN + t * 8 + 4, c1);
        if (t == 0) st_sys_f32(&costpart[bid], 0.0f);
    }
    gridbar(bar, ++bars);

    const float u1 = AVAL / (0.0f + STABV);
    float prev_u = u1;
    float pv_reg = 0.0f;
    {
        f32x4 p0 = ld_sys_f32x4(ksump + (size_t)t * NN + r0);
        f32x4 p1 = ld_sys_f32x4(ksump + (size_t)t * NN + r0 + 4);
#pragma unroll
        for (int off = 32; off > 0; off >>= 1) {
#pragma unroll
            for (int q = 0; q < 4; ++q) {
                p0[q] += __shfl_down(p0[q], off, 64);
                p1[q] += __shfl_down(p1[q], off, 64);
            }
        }
        if (lane == 0) {
            st_sys_f32x4(wsred + bid * 64 + r8 * 8, p0);
            st_sys_f32x4(wsred + bid * 64 + r8 * 8 + 4, p1);
        }
        asm volatile("s_waitcnt vmcnt(0)" ::: "memory");
        __syncthreads();
        if (t < RPB) {
            float ks = 0.0f;
#pragma unroll
            for (int g = 0; g < 8; ++g) ks += ld_sys_f32(wsred + bid * 64 + g * 8 + t);
            st_sys_f32(&u[r0 + t], u1);
            pv_reg = BVAL / (u1 * ks + STABV);
            st_sys_f32(&v[r0 + t], pv_reg);
        }
    }
    gridbar(bar, ++bars);

    for (int it = 2; it <= MAX_IT; ++it) {
        if (t == 0) {
            st_sys_f32(&costpart[bid], 0.0f);
            asm volatile("s_waitcnt vmcnt(0)" ::: "memory");
        }
        __syncthreads();
        f32x4 vr[16];
        if (it == 2) {
#pragma unroll
            for (int k = 0; k < 8; ++k) {
                vr[2 * k]     = *(const f32x4*)(v + lane * 8 + k * 512);
                vr[2 * k + 1] = *(const f32x4*)(v + lane * 8 + k * 512 + 4);
            }
        } else {
#pragma unroll
            for (int k = 0; k < 8; ++k) {
                vr[2 * k]     = ld_sys_f32x4(v + lane * 8 + k * 512);
                vr[2 * k + 1] = ld_sys_f32x4(v + lane * 8 + k * 512 + 4);
            }
        }
        float acc = 0.0f, ts = 0.0f;
#pragma unroll
        for (int k = 0; k < 8; ++k) {
            uint4 cw = *(const uint4*)(Cs + r8 * 8192 + lane * 16 + k * 1024);
            f32x4 v0 = vr[2 * k], v1 = vr[2 * k + 1];
            float c, t1;
            c = bflo(cw.x); t1 = __expf(c * nrs) * v0.x; acc += t1; ts += t1 * c;
            c = bfhi(cw.x); t1 = __expf(c * nrs) * v0.y; acc += t1; ts += t1 * c;
            c = bflo(cw.y); t1 = __expf(c * nrs) * v0.z; acc += t1; ts += t1 * c;
            c = bfhi(cw.y); t1 = __expf(c * nrs) * v0.w; acc += t1; ts += t1 * c;
            c = bflo(cw.z); t1 = __expf(c * nrs) * v1.x; acc += t1; ts += t1 * c;
            c = bfhi(cw.z); t1 = __expf(c * nrs) * v1.y; acc += t1; ts += t1 * c;
            c = bflo(cw.w); t1 = __expf(c * nrs) * v1.z; acc += t1; ts += t1 * c;
            c = bfhi(cw.w); t1 = __expf(c * nrs) * v1.w; acc += t1; ts += t1 * c;
        }
#pragma unroll
        for (int off = 32; off > 0; off >>= 1) {
            acc += __shfl_down(acc, off, 64);
            ts += __shfl_down(ts, off, 64);
        }
        if (lane == 0) {
            float un = AVAL / (acc + STABV);
            if (un != prev_u)
                __hip_atomic_store(&flags[it & 1], 1u, __ATOMIC_RELAXED, __HIP_MEMORY_SCOPE_AGENT);
            prev_u = un;
            st_sys_f32(&u[r0 + r8], un);
            atomicAdd(&costpart[bid], un * ts * invMean);
        }
        if (bid == 0 && t == 0)
            __hip_atomic_store(&flags[(it + 1) & 1], 0u, __ATOMIC_RELAXED, __HIP_MEMORY_SCOPE_AGENT);
        gridbar(bar, ++bars);

        unsigned fl = __hip_atomic_load(&flags[it & 1], __ATOMIC_RELAXED, __HIP_MEMORY_SCOPE_AGENT);
        if (fl == 0u) break;

        {
            float uw[8];
#pragma unroll
            for (int r = 0; r < RPB; ++r) uw[r] = ld_sys_f32(&u[r0 + r]);
            float cp[8] = {0, 0, 0, 0, 0, 0, 0, 0};
#pragma unroll
            for (int r = 0; r < RPB; ++r) {
                uint4 cw = *(const uint4*)(Cs + r * 8192 + t * 16);
                cp[0] += __expf(bflo(cw.x) * nrs) * uw[r];
                cp[1] += __expf(bfhi(cw.x) * nrs) * uw[r];
                cp[2] += __expf(bflo(cw.y) * nrs) * uw[r];
                cp[3] += __expf(bfhi(cw.y) * nrs) * uw[r];
                cp[4] += __expf(bflo(cw.z) * nrs) * uw[r];
                cp[5] += __expf(bfhi(cw.z) * nrs) * uw[r];
                cp[6] += __expf(bflo(cw.w) * nrs) * uw[r];
                cp[7] += __expf(bfhi(cw.w) * nrs) * uw[r];
            }
            f32x4 c0 = {cp[0], cp[1], cp[2], cp[3]};
            f32x4 c1 = {cp[4], cp[5], cp[6], cp[7]};
            st_sys_f32x4(ksump + (size_t)bid * NN + t * 8, c0);
            st_sys_f32x4(ksump + (size_t)bid * NN + t * 8 + 4, c1);
        }
        gridbar(bar, ++bars);
        {
            f32x4 p0 = ld_sys_f32x4(ksump + (size_t)t * NN + r0);
            f32x4 p1 = ld_sys_f32x4(ksump + (size_t)t * NN + r0 + 4);
#pragma unroll
            for (int off = 32; off > 0; off >>= 1) {
#pragma unroll
                for (int q = 0; q < 4; ++q) {
                    p0[q] += __shfl_down(p0[q], off, 64);
                    p1[q] += __shfl_down(p1[q], off, 64);
                }
            }
            if (lane == 0) {
                st_sys_f32x4(wsred + bid * 64 + r8 * 8, p0);
                st_sys_f32x4(wsred + bid * 64 + r8 * 8 + 4, p1);
            }
            asm volatile("s_waitcnt vmcnt(0)" ::: "memory");
            __syncthreads();
            if (t < RPB) {
                float sv = 0.0f;
#pragma unroll
                for (int g = 0; g < 8; ++g) sv += ld_sys_f32(wsred + bid * 64 + g * 8 + t);
                pv_reg = BVAL / (sv + STABV);
                st_sys_f32(&v[r0 + t], pv_reg);
            }
        }
        gridbar(bar, ++bars);
    }

    if (lane == 0) out[1 + r0 + r8] = prev_u;
    if (t < RPB) out[1 + NN + r0 + t] = pv_reg;
    if (bid == 0) {
        float* red = (float*)Cs;
        red[t] = ld_sys_f32(&costpart[t]);
        __syncthreads();
        for (int off = 256; off > 0; off >>= 1) {
            if (t < off) red[t] += red[t + off];
            __syncthreads();
        }
        if (t == 0) out[0] = red[0];
    }
}

extern "C" void kernel_launch(void* const* d_in, const int* in_sizes, int n_in,
                              void* d_out, int out_size, void* d_ws, size_t ws_size,
                              hipStream_t stream) {
    const float* x = (const float*)d_in[0];
    const float* y = (const float*)d_in[1];
    float* out = (float*)d_out;

    // ws layout (C is never materialized)
    unsigned short* xb = (unsigned short*)d_ws;          // N*D bf16
    unsigned short* yb = xb + (size_t)NN * DD;           // N*D bf16
    float* fbase = (float*)(yb + (size_t)NN * DD);
    float* x2    = fbase;                                // N
    float* y2    = x2 + NN;                              // N
    float* u     = y2 + NN;                              // N
    float* v     = u + NN;                               // N
    float* ksump = v + NN;                               // NB*N = 8 MB (colsum partials, fallback)
    float* wsred = ksump + (size_t)NB * NN;              // NB*64 (cross-wave scratch, fallback)
    float* costpart = wsred + NB * 64;                   // 512
    float* sumC  = costpart + NB;                        // 1
    unsigned* minb  = (unsigned*)(sumC + 1);             // 1 (min C bits)
    unsigned* flags = minb + 1;                          // 2
    unsigned* bar   = flags + 3;                         // 384

    size_t need = (2 * (size_t)NN * DD) * 2
                + ((size_t)4 * NN + (size_t)NB * NN + NB * 64 + NB + 8) * sizeof(float)
                + 400 * sizeof(unsigned);
    if (ws_size < need) return;

    hipFuncSetAttribute((const void*)sk_gemm_kernel,
                        hipFuncAttributeMaxDynamicSharedMemorySize, 65536);
    hipFuncSetAttribute((const void*)sk_coop_kernel,
                        hipFuncAttributeMaxDynamicSharedMemorySize, 65536);

    sk_conv_kernel<<<dim3(2 * NN / 4), dim3(256), 0, stream>>>(x, y, xb, yb, x2, y2, sumC, minb, flags, bar);
    sk_gemm_kernel<<<dim3(NN / 64, NN / 64), dim3(256), 65536, stream>>>(xb, yb, x2, y2, sumC, minb);
    sk_coop_kernel<<<dim3(NB), dim3(512), 65536, stream>>>(xb, yb, x2, y2, u, v, ksump, wsred,
                                                           sumC, minb, flags, costpart, bar, out);
}

// Round 17
// 101.623 us; speedup vs baseline: 1.7363x; 1.7363x over previous
//
#include <hip/hip_runtime.h>
#include <math.h>

#define NN 4096
#define DD 256
#define EPSV 1e-4f
#define STABV 1e-8f
#define AVAL (1.0f / 4096.0f)
#define BVAL (1.0f / 4096.0f)
#define MAX_IT 2000
#define NB 512           // coop grid: 512 blocks x 512 thr
#define RPB 8            // rows (and cols) owned per block
#define UFLOW_M 192.0f   // if min(C)*|nrs| >= this, every exp() underflows to exactly 0.0f

typedef __attribute__((ext_vector_type(4))) float f32x4;
typedef __attribute__((ext_vector_type(8))) short bf16x8;

__device__ inline unsigned short f2bf(float f) {   // RNE f32->bf16
    unsigned u = __float_as_uint(f);
    return (unsigned short)((u + 0x7fffu + ((u >> 16) & 1u)) >> 16);
}
__device__ inline float bflo(unsigned w) { return __uint_as_float(w << 16); }
__device__ inline float bfhi(unsigned w) { return __uint_as_float(w & 0xffff0000u); }

// ---- MALL-coherent (cache-bypassing) access for cross-block data inside coop kernel ----
__device__ __forceinline__ void st_sys_f32(float* p, float v) {
    asm volatile("global_store_dword %0, %1, off sc0 sc1" :: "v"(p), "v"(v) : "memory");
}
__device__ __forceinline__ void st_sys_f32x4(float* p, f32x4 v) {
    asm volatile("global_store_dwordx4 %0, %1, off sc0 sc1" :: "v"(p), "v"(v) : "memory");
}
__device__ __forceinline__ float ld_sys_f32(const float* p) {
    float r;
    asm volatile("global_load_dword %0, %1, off sc0 sc1\n\ts_waitcnt vmcnt(0)"
                 : "=v"(r) : "v"(p) : "memory");
    return r;
}
__device__ __forceinline__ f32x4 ld_sys_f32x4(const float* p) {
    f32x4 r;
    asm volatile("global_load_dwordx4 %0, %1, off sc0 sc1\n\ts_waitcnt vmcnt(0)"
                 : "=v"(r) : "v"(p) : "memory");
    return r;
}

// ---------------- conv f32->bf16 + row norms + zero control state ----------------
__global__ __launch_bounds__(256) void sk_conv_kernel(const float* __restrict__ x,
                                                      const float* __restrict__ y,
                                                      unsigned short* __restrict__ xb,
                                                      unsigned short* __restrict__ yb,
                                                      float* __restrict__ x2,
                                                      float* __restrict__ y2,
                                                      float* __restrict__ sumC,
                                                      unsigned* __restrict__ minb,
                                                      unsigned* __restrict__ flags,
                                                      unsigned* __restrict__ bar) {
    int w = blockIdx.x * 4 + (threadIdx.x >> 6);   // row id 0..8191
    int lane = threadIdx.x & 63;
    const float* src = (w < NN) ? (x + (size_t)w * DD) : (y + (size_t)(w - NN) * DD);
    unsigned short* dst = (w < NN) ? (xb + (size_t)w * DD) : (yb + (size_t)(w - NN) * DD);
    float4 v = *(const float4*)(src + lane * 4);
    float sq = v.x * v.x + v.y * v.y + v.z * v.z + v.w * v.w;
    ushort4 p;
    p.x = f2bf(v.x); p.y = f2bf(v.y); p.z = f2bf(v.z); p.w = f2bf(v.w);
    *(ushort4*)(dst + lane * 4) = p;
#pragma unroll
    for (int off = 32; off > 0; off >>= 1) sq += __shfl_down(sq, off, 64);
    if (lane == 0) {
        if (w < NN) x2[w] = sq; else y2[w - NN] = sq;
    }
    int t = threadIdx.x;
    if (blockIdx.x == 0) {
        if (t == 0) { sumC[0] = 0.0f; minb[0] = 0xFFFFFFFFu; flags[0] = 0u; flags[1] = 0u; }
        for (int i = t; i < 384; i += 256) bar[i] = 0u;
    }
}

// ---------------- MFMA GEMM (reduce-only, round-13 structure + XOR bank swizzle) ----------------
// sum(C) and min(C); C is NOT materialized. LDS layout: row r's 16-B chunk at LDS colb holds
// global colb ^ ((r&7)*16). ds_read applies the same XOR -> conflict-free (measured 0 in r15).
__global__ __launch_bounds__(256) void sk_gemm_kernel(const unsigned short* __restrict__ xb,
                                                      const unsigned short* __restrict__ yb,
                                                      const float* __restrict__ x2,
                                                      const float* __restrict__ y2,
                                                      float* __restrict__ sumC,
                                                      unsigned* __restrict__ minb) {
    __shared__ __attribute__((aligned(128))) char AsB[16384];  // A tile 128 rows x 64 k (bf16), 128 B/row
    __shared__ __attribute__((aligned(128))) char BsB[16384];  // B tile
    __shared__ float red[256];
    __shared__ float red2[256];
    const int tid = threadIdx.x;
    const int wid = tid >> 6, lane = tid & 63;
    const int wy = wid >> 1, wx = wid & 1;
    const int rb0 = blockIdx.y * 128, cb0 = blockIdx.x * 128;
    const int lr = lane & 15;
    const int lq = lane >> 4;
    const int srow8 = tid >> 3;              // staging row-within-chunk 0..31
    const int scolb = (tid & 7) * 16;        // lane's fixed LDS colb within row
    const int sgcol = scolb ^ ((srow8 & 7) * 16);   // swizzled global colb this lane fetches

    f32x4 acc[4][4];
    const f32x4 z4 = {0.0f, 0.0f, 0.0f, 0.0f};
#pragma unroll
    for (int a = 0; a < 4; ++a)
#pragma unroll
        for (int b = 0; b < 4; ++b) acc[a][b] = z4;

    for (int s = 0; s < 4; ++s) {
        const int k0 = s * 64;
        if (s) __syncthreads();
#pragma unroll
        for (int c = 0; c < 4; ++c) {
            const char* ga = (const char*)xb + ((size_t)(rb0 + c * 32 + srow8) * DD + k0) * 2 + sgcol;
            __builtin_amdgcn_global_load_lds(
                (const __attribute__((address_space(1))) void*)ga,
                (__attribute__((address_space(3))) void*)(AsB + c * 4096 + wid * 1024), 16, 0, 0);
        }
#pragma unroll
        for (int c = 0; c < 4; ++c) {
            const char* gb = (const char*)yb + ((size_t)(cb0 + c * 32 + srow8) * DD + k0) * 2 + sgcol;
            __builtin_amdgcn_global_load_lds(
                (const __attribute__((address_space(1))) void*)gb,
                (__attribute__((address_space(3))) void*)(BsB + c * 4096 + wid * 1024), 16, 0, 0);
        }
        asm volatile("s_waitcnt vmcnt(0)" ::: "memory");
        __syncthreads();
#pragma unroll
        for (int m = 0; m < 2; ++m) {
            const int swz = (lr & 7) * 16;   // row&7 == lr&7 (row = wy*64 + t*16 + lr)
            const int cofs = (m * 64 + lq * 16) ^ swz;
            bf16x8 af[4], bfr[4];
#pragma unroll
            for (int t = 0; t < 4; ++t)
                af[t] = *(const bf16x8*)(AsB + (wy * 64 + t * 16 + lr) * 128 + cofs);
#pragma unroll
            for (int t = 0; t < 4; ++t)
                bfr[t] = *(const bf16x8*)(BsB + (wx * 64 + t * 16 + lr) * 128 + cofs);
#pragma unroll
            for (int ty = 0; ty < 4; ++ty)
#pragma unroll
                for (int tx = 0; tx < 4; ++tx)
                    acc[ty][tx] = __builtin_amdgcn_mfma_f32_16x16x32_bf16(af[ty], bfr[tx], acc[ty][tx], 0, 0, 0);
        }
    }

    float lsum = 0.0f, lmin = 3.0e38f;
    const int qr = lq * 4;
#pragma unroll
    for (int ty = 0; ty < 4; ++ty) {
        float x2r[4];
#pragma unroll
        for (int r = 0; r < 4; ++r)
            x2r[r] = x2[rb0 + wy * 64 + ty * 16 + qr + r];
#pragma unroll
        for (int tx = 0; tx < 4; ++tx) {
            int col = cb0 + wx * 64 + tx * 16 + lr;
            float y2c = y2[col];
#pragma unroll
            for (int r = 0; r < 4; ++r) {
                float sq = x2r[r] + y2c - 2.0f * acc[ty][tx][r];
                float c = sqrtf(fmaxf(sq, 0.0f));
                lsum += c;
                lmin = fminf(lmin, c);
            }
        }
    }
    red[tid] = lsum;
    red2[tid] = lmin;
    __syncthreads();
    for (int off = 128; off > 0; off >>= 1) {
        if (tid < off) {
            red[tid] += red[tid + off];
            red2[tid] = fminf(red2[tid], red2[tid + off]);
        }
        __syncthreads();
    }
    if (tid == 0) {
        atomicAdd(sumC, red[0]);
        atomicMin(minb, __float_as_uint(red2[0]));   // C >= 0: uint order == float order
    }
}

// ---- fence-free hierarchical grid barrier (cross-block data uses sc0sc1 / atomics) ----
__device__ __forceinline__ void gridbar(unsigned* bar, unsigned target) {
    asm volatile("s_waitcnt vmcnt(0)" ::: "memory");
    __syncthreads();
    if (threadIdx.x == 0) {
        const int sg = blockIdx.x & 7;
        const unsigned bps = NB >> 3;
        unsigned p = __hip_atomic_fetch_add(&bar[sg * 32], 1u, __ATOMIC_RELAXED, __HIP_MEMORY_SCOPE_AGENT);
        if (p == target * bps - 1u) {
            unsigned q = __hip_atomic_fetch_add(&bar[256], 1u, __ATOMIC_RELAXED, __HIP_MEMORY_SCOPE_AGENT);
            if (q == target * 8u - 1u)
                __hip_atomic_store(&bar[288], target, __ATOMIC_RELAXED, __HIP_MEMORY_SCOPE_AGENT);
        }
        while (__hip_atomic_load(&bar[288], __ATOMIC_RELAXED, __HIP_MEMORY_SCOPE_AGENT) < target)
            __builtin_amdgcn_s_sleep(1);
    }
    __syncthreads();
}

// ---------------- Sinkhorn finalize ----------------
// Fast path (min(C)*|nrs| >= UFLOW_M): every exp underflows to exactly 0.0f in f32 =>
// K == 0 bitwise => u = a/stab, v = b/stab (fixed point at it=2), cost = 0. Analytic.
// Generic fallback: recompute owned C rows from xb/yb into LDS, run verified iteration loop.
__global__ __launch_bounds__(512, 4) void sk_coop_kernel(const unsigned short* __restrict__ xb,
                                                         const unsigned short* __restrict__ yb,
                                                         const float* __restrict__ x2,
                                                         const float* __restrict__ y2,
                                                         float* __restrict__ u,
                                                         float* __restrict__ v,
                                                         float* __restrict__ ksump,
                                                         float* __restrict__ wsred,
                                                         const float* __restrict__ sumC,
                                                         const unsigned* __restrict__ minb,
                                                         unsigned* __restrict__ flags,
                                                         float* __restrict__ costpart,
                                                         unsigned* __restrict__ bar,
                                                         float* __restrict__ out) {
    extern __shared__ char Cs[];       // 65536 B: 8 rows x 8192 B (bf16 x 4096), fallback only
    const int t = threadIdx.x;         // 0..511
    const int bid = blockIdx.x;
    const int r8 = t >> 6;             // wave id 0..7 == owned row index
    const int lane = t & 63;
    const float mean = sumC[0] * (1.0f / ((float)NN * (float)NN));
    const float nrs = -1.0f / (mean * EPSV);   // K = exp(C_raw * nrs), nrs < 0
    const float invMean = 1.0f / mean;
    const int r0 = bid * RPB;
    unsigned bars = 0;

    // ---- underflow fast path (grid-uniform branch) ----
    const float minC = __uint_as_float(minb[0]);
    const float m = minC * (-nrs);
    if (m >= UFLOW_M) {
        const float uval = AVAL / (0.0f + STABV);
        const float vval = BVAL / (0.0f + STABV);
        if (lane == 0) out[1 + r0 + r8] = uval;
        if (t < RPB) out[1 + NN + r0 + t] = vval;
        if (bid == 0 && t == 0) out[0] = 0.0f;
        return;
    }

    // ================= generic fallback (not taken for this input) =================
    {
        float x2r[8];
#pragma unroll
        for (int r = 0; r < RPB; ++r) x2r[r] = x2[r0 + r];
        float cp[8] = {0, 0, 0, 0, 0, 0, 0, 0};
        for (int r = 0; r < RPB; ++r) {
            alignas(16) unsigned short crow[8];
#pragma unroll
            for (int q = 0; q < 8; ++q) {
                int j = t * 8 + q;
                float s = 0.0f;
                for (int k = 0; k < DD; k += 8) {
                    uint4 xa = *(const uint4*)(xb + (size_t)(r0 + r) * DD + k);
                    uint4 ya = *(const uint4*)(yb + (size_t)j * DD + k);
                    s += bflo(xa.x) * bflo(ya.x) + bfhi(xa.x) * bfhi(ya.x);
                    s += bflo(xa.y) * bflo(ya.y) + bfhi(xa.y) * bfhi(ya.y);
                    s += bflo(xa.z) * bflo(ya.z) + bfhi(xa.z) * bfhi(ya.z);
                    s += bflo(xa.w) * bflo(ya.w) + bfhi(xa.w) * bfhi(ya.w);
                }
                float c = sqrtf(fmaxf(x2r[r] + y2[j] - 2.0f * s, 0.0f));
                unsigned short cb = f2bf(c);
                crow[q] = cb;
                cp[q] += __expf(bflo((unsigned)cb) * nrs);
            }
            *(uint4*)(Cs + r * 8192 + t * 16) = *(const uint4*)crow;
        }
        f32x4 c0 = {cp[0], cp[1], cp[2], cp[3]};
        f32x4 c1 = {cp[4], cp[5], cp[6], cp[7]};
        st_sys_f32x4(ksump + (size_t)bid * NN + t * 8, c0);
        st_sys_f32x4(ksump + (size_t)bid * NN + t * 8 + 4, c1);
        if (t == 0) st_sys_f32(&costpart[bid], 0.0f);
    }
    gridbar(bar, ++bars);

    const float u1 = AVAL / (0.0f + STABV);
    float prev_u = u1;
    float pv_reg = 0.0f;
    {
        f32x4 p0 = ld_sys_f32x4(ksump + (size_t)t * NN + r0);
        f32x4 p1 = ld_sys_f32x4(ksump + (size_t)t * NN + r0 + 4);
#pragma unroll
        for (int off = 32; off > 0; off >>= 1) {
#pragma unroll
            for (int q = 0; q < 4; ++q) {
                p0[q] += __shfl_down(p0[q], off, 64);
                p1[q] += __shfl_down(p1[q], off, 64);
            }
        }
        if (lane == 0) {
            st_sys_f32x4(wsred + bid * 64 + r8 * 8, p0);
            st_sys_f32x4(wsred + bid * 64 + r8 * 8 + 4, p1);
        }
        asm volatile("s_waitcnt vmcnt(0)" ::: "memory");
        __syncthreads();
        if (t < RPB) {
            float ks = 0.0f;
#pragma unroll
            for (int g = 0; g < 8; ++g) ks += ld_sys_f32(wsred + bid * 64 + g * 8 + t);
            st_sys_f32(&u[r0 + t], u1);
            pv_reg = BVAL / (u1 * ks + STABV);
            st_sys_f32(&v[r0 + t], pv_reg);
        }
    }
    gridbar(bar, ++bars);

    for (int it = 2; it <= MAX_IT; ++it) {
        if (t == 0) {
            st_sys_f32(&costpart[bid], 0.0f);
            asm volatile("s_waitcnt vmcnt(0)" ::: "memory");
        }
        __syncthreads();
        f32x4 vr[16];
        if (it == 2) {
#pragma unroll
            for (int k = 0; k < 8; ++k) {
                vr[2 * k]     = *(const f32x4*)(v + lane * 8 + k * 512);
                vr[2 * k + 1] = *(const f32x4*)(v + lane * 8 + k * 512 + 4);
            }
        } else {
#pragma unroll
            for (int k = 0; k < 8; ++k) {
                vr[2 * k]     = ld_sys_f32x4(v + lane * 8 + k * 512);
                vr[2 * k + 1] = ld_sys_f32x4(v + lane * 8 + k * 512 + 4);
            }
        }
        float acc = 0.0f, ts = 0.0f;
#pragma unroll
        for (int k = 0; k < 8; ++k) {
            uint4 cw = *(const uint4*)(Cs + r8 * 8192 + lane * 16 + k * 1024);
            f32x4 v0 = vr[2 * k], v1 = vr[2 * k + 1];
            float c, t1;
            c = bflo(cw.x); t1 = __expf(c * nrs) * v0.x; acc += t1; ts += t1 * c;
            c = bfhi(cw.x); t1 = __expf(c * nrs) * v0.y; acc += t1; ts += t1 * c;
            c = bflo(cw.y); t1 = __expf(c * nrs) * v0.z; acc += t1; ts += t1 * c;
            c = bfhi(cw.y); t1 = __expf(c * nrs) * v0.w; acc += t1; ts += t1 * c;
            c = bflo(cw.z); t1 = __expf(c * nrs) * v1.x; acc += t1; ts += t1 * c;
            c = bfhi(cw.z); t1 = __expf(c * nrs) * v1.y; acc += t1; ts += t1 * c;
            c = bflo(cw.w); t1 = __expf(c * nrs) * v1.z; acc += t1; ts += t1 * c;
            c = bfhi(cw.w); t1 = __expf(c * nrs) * v1.w; acc += t1; ts += t1 * c;
        }
#pragma unroll
        for (int off = 32; off > 0; off >>= 1) {
            acc += __shfl_down(acc, off, 64);
            ts += __shfl_down(ts, off, 64);
        }
        if (lane == 0) {
            float un = AVAL / (acc + STABV);
            if (un != prev_u)
                __hip_atomic_store(&flags[it & 1], 1u, __ATOMIC_RELAXED, __HIP_MEMORY_SCOPE_AGENT);
            prev_u = un;
            st_sys_f32(&u[r0 + r8], un);
            atomicAdd(&costpart[bid], un * ts * invMean);
        }
        if (bid == 0 && t == 0)
            __hip_atomic_store(&flags[(it + 1) & 1], 0u, __ATOMIC_RELAXED, __HIP_MEMORY_SCOPE_AGENT);
        gridbar(bar, ++bars);

        unsigned fl = __hip_atomic_load(&flags[it & 1], __ATOMIC_RELAXED, __HIP_MEMORY_SCOPE_AGENT);
        if (fl == 0u) break;

        {
            float uw[8];
#pragma unroll
            for (int r = 0; r < RPB; ++r) uw[r] = ld_sys_f32(&u[r0 + r]);
            float cp[8] = {0, 0, 0, 0, 0, 0, 0, 0};
#pragma unroll
            for (int r = 0; r < RPB; ++r) {
                uint4 cw = *(const uint4*)(Cs + r * 8192 + t * 16);
                cp[0] += __expf(bflo(cw.x) * nrs) * uw[r];
                cp[1] += __expf(bfhi(cw.x) * nrs) * uw[r];
                cp[2] += __expf(bflo(cw.y) * nrs) * uw[r];
                cp[3] += __expf(bfhi(cw.y) * nrs) * uw[r];
                cp[4] += __expf(bflo(cw.z) * nrs) * uw[r];
                cp[5] += __expf(bfhi(cw.z) * nrs) * uw[r];
                cp[6] += __expf(bflo(cw.w) * nrs) * uw[r];
                cp[7] += __expf(bfhi(cw.w) * nrs) * uw[r];
            }
            f32x4 c0 = {cp[0], cp[1], cp[2], cp[3]};
            f32x4 c1 = {cp[4], cp[5], cp[6], cp[7]};
            st_sys_f32x4(ksump + (size_t)bid * NN + t * 8, c0);
            st_sys_f32x4(ksump + (size_t)bid * NN + t * 8 + 4, c1);
        }
        gridbar(bar, ++bars);
        {
            f32x4 p0 = ld_sys_f32x4(ksump + (size_t)t * NN + r0);
            f32x4 p1 = ld_sys_f32x4(ksump + (size_t)t * NN + r0 + 4);
#pragma unroll
            for (int off = 32; off > 0; off >>= 1) {
#pragma unroll
                for (int q = 0; q < 4; ++q) {
                    p0[q] += __shfl_down(p0[q], off, 64);
                    p1[q] += __shfl_down(p1[q], off, 64);
                }
            }
            if (lane == 0) {
                st_sys_f32x4(wsred + bid * 64 + r8 * 8, p0);
                st_sys_f32x4(wsred + bid * 64 + r8 * 8 + 4, p1);
            }
            asm volatile("s_waitcnt vmcnt(0)" ::: "memory");
            __syncthreads();
            if (t < RPB) {
                float sv = 0.0f;
#pragma unroll
                for (int g = 0; g < 8; ++g) sv += ld_sys_f32(wsred + bid * 64 + g * 8 + t);
                pv_reg = BVAL / (sv + STABV);
                st_sys_f32(&v[r0 + t], pv_reg);
            }
        }
        gridbar(bar, ++bars);
    }

    if (lane == 0) out[1 + r0 + r8] = prev_u;
    if (t < RPB) out[1 + NN + r0 + t] = pv_reg;
    if (bid == 0) {
        float* red = (float*)Cs;
        red[t] = ld_sys_f32(&costpart[t]);
        __syncthreads();
        for (int off = 256; off > 0; off >>= 1) {
            if (t < off) red[t] += red[t + off];
            __syncthreads();
        }
        if (t == 0) out[0] = red[0];
    }
}

extern "C" void kernel_launch(void* const* d_in, const int* in_sizes, int n_in,
                              void* d_out, int out_size, void* d_ws, size_t ws_size,
                              hipStream_t stream) {
    const float* x = (const float*)d_in[0];
    const float* y = (const float*)d_in[1];
    float* out = (float*)d_out;

    // ws layout (C is never materialized)
    unsigned short* xb = (unsigned short*)d_ws;          // N*D bf16
    unsigned short* yb = xb + (size_t)NN * DD;           // N*D bf16
    float* fbase = (float*)(yb + (size_t)NN * DD);
    float* x2    = fbase;                                // N
    float* y2    = x2 + NN;                              // N
    float* u     = y2 + NN;                              // N
    float* v     = u + NN;                               // N
    float* ksump = v + NN;                               // NB*N = 8 MB (colsum partials, fallback)
    float* wsred = ksump + (size_t)NB * NN;              // NB*64 (cross-wave scratch, fallback)
    float* costpart = wsred + NB * 64;                   // 512
    float* sumC  = costpart + NB;                        // 1
    unsigned* minb  = (unsigned*)(sumC + 1);             // 1 (min C bits)
    unsigned* flags = minb + 1;                          // 2
    unsigned* bar   = flags + 3;                         // 384

    size_t need = (2 * (size_t)NN * DD) * 2
                + ((size_t)4 * NN + (size_t)NB * NN + NB * 64 + NB + 8) * sizeof(float)
                + 400 * sizeof(unsigned);
    if (ws_size < need) return;

    hipFuncSetAttribute((const void*)sk_coop_kernel,
                        hipFuncAttributeMaxDynamicSharedMemorySize, 65536);

    sk_conv_kernel<<<dim3(2 * NN / 4), dim3(256), 0, stream>>>(x, y, xb, yb, x2, y2, sumC, minb, flags, bar);
    sk_gemm_kernel<<<dim3(NN / 128, NN / 128), dim3(256), 0, stream>>>(xb, yb, x2, y2, sumC, minb);
    sk_coop_kernel<<<dim3(NB), dim3(512), 65536, stream>>>(xb, yb, x2, y2, u, v, ksump, wsred,
                                                           sumC, minb, flags, costpart, bar, out);
}